// Round 7
// baseline (1154.279 us; speedup 1.0000x reference)
//
#include <hip/hip_runtime.h>
#include <stdint.h>

#define NN 8192
#define FF 256
#define HH 64

typedef __attribute__((ext_vector_type(8))) short bf16x8;
typedef __attribute__((ext_vector_type(4))) float f32x4;

__device__ __forceinline__ uint16_t f2bf(float f) {
  union { float f; uint32_t i; } c; c.f = f;
  uint32_t r = c.i + 0x7FFFu + ((c.i >> 16) & 1u);
  return (uint16_t)(r >> 16);
}

// ---------------------------------------------------------------------------
// K1 (VERIFIED r5, verbatim): h = x @ Wt^T + bt (fp32), h[node][c].
// ---------------------------------------------------------------------------
__global__ __launch_bounds__(256) void k1_h(
    const float* __restrict__ x, const float* __restrict__ Wt,
    const float* __restrict__ bt, float* __restrict__ h) {
  __shared__ float wtT[256 * 65];
  __shared__ float sbt[64];
  const int t = threadIdx.x;
  const int lane = t & 63;
  const int w = t >> 6;

  for (int i = 0; i < 64; ++i)
    wtT[t * 65 + i] = Wt[(size_t)i * FF + t];
  if (t < 64) sbt[t] = bt[t];
  __syncthreads();

  const int r0 = blockIdx.x * 32 + w * 8;
  const float binit = sbt[lane];
  float acc[8];
#pragma unroll
  for (int r = 0; r < 8; ++r) acc[r] = binit;

  for (int f4 = 0; f4 < FF; f4 += 4) {
    float4 xs[8];
#pragma unroll
    for (int r = 0; r < 8; ++r)
      xs[r] = *(const float4*)(x + (size_t)(r0 + r) * FF + f4);
    const float wt0 = wtT[(f4 + 0) * 65 + lane];
    const float wt1 = wtT[(f4 + 1) * 65 + lane];
    const float wt2 = wtT[(f4 + 2) * 65 + lane];
    const float wt3 = wtT[(f4 + 3) * 65 + lane];
#pragma unroll
    for (int r = 0; r < 8; ++r)
      acc[r] += xs[r].x * wt0 + xs[r].y * wt1 + xs[r].z * wt2 + xs[r].w * wt3;
  }
#pragma unroll
  for (int r = 0; r < 8; ++r)
    h[(size_t)(r0 + r) * HH + lane] = acc[r];
}

// ---------------------------------------------------------------------------
// K1b: hT[c][n] = bf16(h[n][c]). 64x64 LDS tile transpose. grid=128.
// ---------------------------------------------------------------------------
__global__ __launch_bounds__(256) void k1b_hT(
    const float* __restrict__ h, uint16_t* __restrict__ hT) {
  __shared__ float s[64][65];
  const int t = threadIdx.x;
  const int n0 = blockIdx.x * 64;
  for (int i = 0; i < 16; ++i) {
    int idx = i * 256 + t;
    int r = idx >> 6, c = idx & 63;
    s[r][c] = h[(size_t)(n0 + r) * HH + c];
  }
  __syncthreads();
  for (int i = 0; i < 16; ++i) {
    int idx = i * 256 + t;
    int c = idx >> 6, n = idx & 63;
    hT[(size_t)c * NN + n0 + n] = f2bf(s[n][c]);
  }
}

// ---------------------------------------------------------------------------
// K2 diagnostic: output ALWAYS from verified VALU path (pass guaranteed).
// MFMA path computed in parallel and compared; mismatch class -> spin time.
// block = 256 (4 waves), 16 rows/block, grid = 512.
// ---------------------------------------------------------------------------
__global__ __launch_bounds__(256) void k2_diag(
    const float* __restrict__ x, const int* __restrict__ adj,
    const float* __restrict__ h, const uint16_t* __restrict__ hT,
    const float* __restrict__ Wp, const float* __restrict__ bp,
    const float* __restrict__ gamma, const float* __restrict__ beta,
    float* __restrict__ out, int mode) {
  __shared__ float s_partV[4][16][64];
  __shared__ int   s_degpV[4][16];
  __shared__ float s_nbV[16][64];
  __shared__ int   s_degVt[16];
  __shared__ float s_partM[4][16][64];
  __shared__ int   s_degM[16];
  __shared__ float s_y[16 * 256];
  __shared__ int   s_flags;

  const int t    = threadIdx.x;
  const int w    = t >> 6;
  const int lane = t & 63;
  const int row0 = blockIdx.x * 16;

  if (t == 0) s_flags = 0;
  if (t < 16) s_degM[t] = 0;
  __syncthreads();

  const int kbeg = w * (NN / 4);
  const int kend = kbeg + (NN / 4);

  // ---- Phase 1: VALU nb (r5-verified structure, 16 rows) ----
  {
    float acc[16];
    int   deg[16];
#pragma unroll
    for (int r = 0; r < 16; ++r) { acc[r] = 0.f; deg[r] = 0; }
    const int* ap[16];
#pragma unroll
    for (int r = 0; r < 16; ++r) ap[r] = adj + (size_t)(row0 + r) * NN;

    for (int jb = kbeg; jb < kend; jb += 4) {
      const float* hb = h + (size_t)jb * HH + lane;
      float v0 = hb[0 * HH];
      float v1 = hb[1 * HH];
      float v2 = hb[2 * HH];
      float v3 = hb[3 * HH];
#pragma unroll
      for (int r = 0; r < 16; ++r) {
        int4 a = *(const int4*)(ap[r] + jb);
        acc[r] += (a.x ? v0 : 0.f) + (a.y ? v1 : 0.f) +
                  (a.z ? v2 : 0.f) + (a.w ? v3 : 0.f);
        deg[r] += a.x + a.y + a.z + a.w;
      }
    }
#pragma unroll
    for (int r = 0; r < 16; ++r) s_partV[w][r][lane] = acc[r];
    if (lane == 0) {
#pragma unroll
      for (int r = 0; r < 16; ++r) s_degpV[w][r] = deg[r];
    }
  }
  __syncthreads();

  for (int idx = t; idx < 16 * 64; idx += 256) {
    int r = idx >> 6, c = idx & 63;
    float sV = s_partV[0][r][c] + s_partV[1][r][c] +
               s_partV[2][r][c] + s_partV[3][r][c];
    int dV = s_degpV[0][r] + s_degpV[1][r] + s_degpV[2][r] + s_degpV[3][r];
    s_nbV[r][c] = (dV > 0) ? sV / (float)dV : 0.f;
    if (c == 0) s_degVt[r] = dV;
  }
  __syncthreads();

  // ---- Phase 2: MFMA nb + compare (mode 0 only) ----
  if (mode == 0) {
    const int m = lane & 15;
    const int q = lane >> 4;
    f32x4 acc0 = 0, acc1 = 0, acc2 = 0, acc3 = 0;
    int degm = 0;
    const int* __restrict__ arow = adj + (size_t)(row0 + m) * NN;
    const uint16_t* __restrict__ hrow = hT + (size_t)m * NN;

    for (int kb = kbeg; kb < kend; kb += 32) {
      const int k0 = kb + q * 8;
      int4 a0 = *(const int4*)(arow + k0);
      int4 a1 = *(const int4*)(arow + k0 + 4);
      degm += a0.x + a0.y + a0.z + a0.w + a1.x + a1.y + a1.z + a1.w;
      bf16x8 af;
      af[0] = a0.x ? (short)0x3F80 : (short)0;
      af[1] = a0.y ? (short)0x3F80 : (short)0;
      af[2] = a0.z ? (short)0x3F80 : (short)0;
      af[3] = a0.w ? (short)0x3F80 : (short)0;
      af[4] = a1.x ? (short)0x3F80 : (short)0;
      af[5] = a1.y ? (short)0x3F80 : (short)0;
      af[6] = a1.z ? (short)0x3F80 : (short)0;
      af[7] = a1.w ? (short)0x3F80 : (short)0;
      bf16x8 b0 = *(const bf16x8*)(hrow + k0);
      bf16x8 b1 = *(const bf16x8*)(hrow + 16 * NN + k0);
      bf16x8 b2 = *(const bf16x8*)(hrow + 32 * NN + k0);
      bf16x8 b3 = *(const bf16x8*)(hrow + 48 * NN + k0);
      acc0 = __builtin_amdgcn_mfma_f32_16x16x32_bf16(af, b0, acc0, 0, 0, 0);
      acc1 = __builtin_amdgcn_mfma_f32_16x16x32_bf16(af, b1, acc1, 0, 0, 0);
      acc2 = __builtin_amdgcn_mfma_f32_16x16x32_bf16(af, b2, acc2, 0, 0, 0);
      acc3 = __builtin_amdgcn_mfma_f32_16x16x32_bf16(af, b3, acc3, 0, 0, 0);
    }

    degm += __shfl_down(degm, 32, 64);
    degm += __shfl_down(degm, 16, 64);
    if (lane < 16) atomicAdd(&s_degM[lane], degm);

#pragma unroll
    for (int rg = 0; rg < 4; ++rg) {
      s_partM[w][q * 4 + rg][ 0 + m] = acc0[rg];
      s_partM[w][q * 4 + rg][16 + m] = acc1[rg];
      s_partM[w][q * 4 + rg][32 + m] = acc2[rg];
      s_partM[w][q * 4 + rg][48 + m] = acc3[rg];
    }
    __syncthreads();

    for (int idx = t; idx < 16 * 64; idx += 256) {
      int r = idx >> 6, c = idx & 63;
      float sM = s_partM[0][r][c] + s_partM[1][r][c] +
                 s_partM[2][r][c] + s_partM[3][r][c];
      int dV = s_degVt[r];
      float nbM = (dV > 0) ? sM / (float)dV : 0.f;
      if (fabsf(nbM - s_nbV[r][c]) > 2e-3f)
        atomicOr(&s_flags, (c < 16) ? 1 : 2);
      if (c == 0 && s_degM[r] != dV) atomicOr(&s_flags, 4);
    }
    __syncthreads();
  }

  // ---- Epilogue (r4-verified) from s_nbV ----
  {
    const int f = t;
    float wp[64];
    const float* wrow = Wp + (size_t)f * HH;
#pragma unroll
    for (int j = 0; j < 16; ++j) {
      float4 v = *(const float4*)(wrow + j * 4);
      wp[j * 4 + 0] = v.x; wp[j * 4 + 1] = v.y;
      wp[j * 4 + 2] = v.z; wp[j * 4 + 3] = v.w;
    }
    const float bpf = bp[f];
    for (int r = 0; r < 16; ++r) {
      float a = bpf;
#pragma unroll
      for (int k = 0; k < 64; k += 4) {
        float4 nv = *(const float4*)&s_nbV[r][k];
        a += nv.x * wp[k] + nv.y * wp[k + 1] + nv.z * wp[k + 2] + nv.w * wp[k + 3];
      }
      float y = x[(size_t)(row0 + r) * FF + f] + a;
      s_y[r * 256 + f] = y;
    }
  }
  __syncthreads();

  for (int i = 0; i < 4; ++i) {
    const int r = w * 4 + i;
    float4 v = *(const float4*)&s_y[r * 256 + lane * 4];
    float sum = v.x + v.y + v.z + v.w;
    float ss  = v.x * v.x + v.y * v.y + v.z * v.z + v.w * v.w;
#pragma unroll
    for (int o = 32; o >= 1; o >>= 1) {
      sum += __shfl_xor(sum, o, 64);
      ss  += __shfl_xor(ss, o, 64);
    }
    const float mu  = sum * (1.0f / 256.0f);
    const float var = ss * (1.0f / 256.0f) - mu * mu;
    const float rs  = rsqrtf(var + 1e-5f);
    const int f0 = lane * 4;
    float4 g = *(const float4*)(gamma + f0);
    float4 b = *(const float4*)(beta + f0);
    float4 o4;
    o4.x = g.x * (v.x - mu) * rs + b.x;
    o4.y = g.y * (v.y - mu) * rs + b.y;
    o4.z = g.z * (v.z - mu) * rs + b.z;
    o4.w = g.w * (v.w - mu) * rs + b.w;
    *(float4*)(out + (size_t)(row0 + r) * FF + f0) = o4;
  }

  // ---- Duration-encoded diagnosis (after all output writes) ----
  int fl = s_flags;
  long long tgt = 0;
  if (mode == 1) tgt = 16000000LL;           // ws too small for hT
  else {
    if (fl & 1) tgt += 1000000LL;            // ch 0-15 mismatch
    if (fl & 2) tgt += 4000000LL;            // ch 16-63 mismatch
    if (fl & 4) tgt += 16000000LL;           // deg mismatch
  }
  if (tgt > 0) {
    long long t0 = clock64();
    while (clock64() - t0 < tgt) { }
  }
}

extern "C" void kernel_launch(void* const* d_in, const int* in_sizes, int n_in,
                              void* d_out, int out_size, void* d_ws, size_t ws_size,
                              hipStream_t stream) {
  const float* x     = (const float*)d_in[0];
  const int*   adj   = (const int*)d_in[1];
  const float* Wt    = (const float*)d_in[2];
  const float* bt    = (const float*)d_in[3];
  // d_in[4] = Wa, d_in[5] = ba: provably dead (softmax scores are row-constant)
  const float* Wp    = (const float*)d_in[6];
  const float* bp    = (const float*)d_in[7];
  const float* gamma = (const float*)d_in[8];
  const float* beta  = (const float*)d_in[9];
  float* out = (float*)d_out;
  float*    h  = (float*)d_ws;                                   // 2 MB fp32
  uint16_t* hT = (uint16_t*)((char*)d_ws + (size_t)NN * HH * 4); // +1 MB bf16

  const int mode = (ws_size >= (size_t)3 * 1024 * 1024) ? 0 : 1;

  k1_h<<<256, 256, 0, stream>>>(x, Wt, bt, h);
  if (mode == 0) k1b_hT<<<128, 256, 0, stream>>>(h, hT);
  k2_diag<<<512, 256, 0, stream>>>(x, adj, h, hT, Wp, bp, gamma, beta, out, mode);
}

// Round 8
// 448.311 us; speedup vs baseline: 2.5747x; 2.5747x over previous
//
#include <hip/hip_runtime.h>
#include <stdint.h>

#define NN 8192
#define FF 256
#define HH 64

typedef __attribute__((ext_vector_type(8))) short bf16x8;
typedef __attribute__((ext_vector_type(4))) float f32x4;

__device__ __forceinline__ uint16_t f2bf(float f) {
  union { float f; uint32_t i; } c; c.f = f;
  uint32_t r = c.i + 0x7FFFu + ((c.i >> 16) & 1u);
  return (uint16_t)(r >> 16);
}

// ---------------------------------------------------------------------------
// K1 (VERIFIED r5, verbatim): h = x @ Wt^T + bt (fp32), h[node][c].
// ---------------------------------------------------------------------------
__global__ __launch_bounds__(256) void k1_h(
    const float* __restrict__ x, const float* __restrict__ Wt,
    const float* __restrict__ bt, float* __restrict__ h) {
  __shared__ float wtT[256 * 65];
  __shared__ float sbt[64];
  const int t = threadIdx.x;
  const int lane = t & 63;
  const int w = t >> 6;

  for (int i = 0; i < 64; ++i)
    wtT[t * 65 + i] = Wt[(size_t)i * FF + t];
  if (t < 64) sbt[t] = bt[t];
  __syncthreads();

  const int r0 = blockIdx.x * 32 + w * 8;
  const float binit = sbt[lane];
  float acc[8];
#pragma unroll
  for (int r = 0; r < 8; ++r) acc[r] = binit;

  for (int f4 = 0; f4 < FF; f4 += 4) {
    float4 xs[8];
#pragma unroll
    for (int r = 0; r < 8; ++r)
      xs[r] = *(const float4*)(x + (size_t)(r0 + r) * FF + f4);
    const float wt0 = wtT[(f4 + 0) * 65 + lane];
    const float wt1 = wtT[(f4 + 1) * 65 + lane];
    const float wt2 = wtT[(f4 + 2) * 65 + lane];
    const float wt3 = wtT[(f4 + 3) * 65 + lane];
#pragma unroll
    for (int r = 0; r < 8; ++r)
      acc[r] += xs[r].x * wt0 + xs[r].y * wt1 + xs[r].z * wt2 + xs[r].w * wt3;
  }
#pragma unroll
  for (int r = 0; r < 8; ++r)
    h[(size_t)(r0 + r) * HH + lane] = acc[r];
}

// ---------------------------------------------------------------------------
// K1b (VERIFIED r7, verbatim): hT[c][n] = bf16(h[n][c]). grid=128.
// ---------------------------------------------------------------------------
__global__ __launch_bounds__(256) void k1b_hT(
    const float* __restrict__ h, uint16_t* __restrict__ hT) {
  __shared__ float s[64][65];
  const int t = threadIdx.x;
  const int n0 = blockIdx.x * 64;
  for (int i = 0; i < 16; ++i) {
    int idx = i * 256 + t;
    int r = idx >> 6, c = idx & 63;
    s[r][c] = h[(size_t)(n0 + r) * HH + c];
  }
  __syncthreads();
  for (int i = 0; i < 16; ++i) {
    int idx = i * 256 + t;
    int c = idx >> 6, n = idx & 63;
    hT[(size_t)c * NN + n0 + n] = f2bf(s[n][c]);
  }
}

// ---------------------------------------------------------------------------
// K2: MFMA core = r7 phase-2 VERBATIM (in-situ verified vs VALU reference,
// flags==0). neighbor_sum = adj @ h via 16x16x32 bf16 MFMA, wave-split-K,
// deg via per-lane adds + shfl + LDS atomic. Epilogue = r4-verified
// tf/residual/LayerNorm. block = 256 (4 waves), 16 rows/block, grid = 512.
// ---------------------------------------------------------------------------
__global__ __launch_bounds__(256) void k2_attn(
    const float* __restrict__ x, const int* __restrict__ adj,
    const uint16_t* __restrict__ hT, const float* __restrict__ Wp,
    const float* __restrict__ bp, const float* __restrict__ gamma,
    const float* __restrict__ beta, float* __restrict__ out) {
  __shared__ float s_part[4][16][64];   // 16 KB partial D
  __shared__ float s_nb[16][64];        // 4 KB neighbor post /deg
  __shared__ float s_y[16 * 256];       // 16 KB y = x + tf
  __shared__ int   s_deg[16];

  const int t    = threadIdx.x;
  const int w    = t >> 6;
  const int lane = t & 63;
  const int m    = lane & 15;
  const int q    = lane >> 4;
  const int row0 = blockIdx.x * 16;

  if (t < 16) s_deg[t] = 0;
  __syncthreads();

  const int kbeg = w * (NN / 4);
  const int kend = kbeg + (NN / 4);

  f32x4 acc0 = 0, acc1 = 0, acc2 = 0, acc3 = 0;
  int degm = 0;
  const int* __restrict__ arow = adj + (size_t)(row0 + m) * NN;
  const uint16_t* __restrict__ hrow = hT + (size_t)m * NN;

  for (int kb = kbeg; kb < kend; kb += 32) {
    const int k0 = kb + q * 8;
    int4 a0 = *(const int4*)(arow + k0);
    int4 a1 = *(const int4*)(arow + k0 + 4);
    degm += a0.x + a0.y + a0.z + a0.w + a1.x + a1.y + a1.z + a1.w;
    bf16x8 af;
    af[0] = a0.x ? (short)0x3F80 : (short)0;
    af[1] = a0.y ? (short)0x3F80 : (short)0;
    af[2] = a0.z ? (short)0x3F80 : (short)0;
    af[3] = a0.w ? (short)0x3F80 : (short)0;
    af[4] = a1.x ? (short)0x3F80 : (short)0;
    af[5] = a1.y ? (short)0x3F80 : (short)0;
    af[6] = a1.z ? (short)0x3F80 : (short)0;
    af[7] = a1.w ? (short)0x3F80 : (short)0;
    bf16x8 b0 = *(const bf16x8*)(hrow + k0);
    bf16x8 b1 = *(const bf16x8*)(hrow + 16 * NN + k0);
    bf16x8 b2 = *(const bf16x8*)(hrow + 32 * NN + k0);
    bf16x8 b3 = *(const bf16x8*)(hrow + 48 * NN + k0);
    acc0 = __builtin_amdgcn_mfma_f32_16x16x32_bf16(af, b0, acc0, 0, 0, 0);
    acc1 = __builtin_amdgcn_mfma_f32_16x16x32_bf16(af, b1, acc1, 0, 0, 0);
    acc2 = __builtin_amdgcn_mfma_f32_16x16x32_bf16(af, b2, acc2, 0, 0, 0);
    acc3 = __builtin_amdgcn_mfma_f32_16x16x32_bf16(af, b3, acc3, 0, 0, 0);
  }

  degm += __shfl_down(degm, 32, 64);
  degm += __shfl_down(degm, 16, 64);
  if (lane < 16) atomicAdd(&s_deg[lane], degm);

#pragma unroll
  for (int rg = 0; rg < 4; ++rg) {
    s_part[w][q * 4 + rg][ 0 + m] = acc0[rg];
    s_part[w][q * 4 + rg][16 + m] = acc1[rg];
    s_part[w][q * 4 + rg][32 + m] = acc2[rg];
    s_part[w][q * 4 + rg][48 + m] = acc3[rg];
  }
  __syncthreads();

  // cross-wave reduce + /deg
  for (int idx = t; idx < 16 * 64; idx += 256) {
    int r = idx >> 6, c = idx & 63;
    float s = s_part[0][r][c] + s_part[1][r][c] +
              s_part[2][r][c] + s_part[3][r][c];
    int d = s_deg[r];
    s_nb[r][c] = (d > 0) ? s / (float)d : 0.f;
  }
  __syncthreads();

  // tf = neighbor @ Wp^T + bp ; y = x + tf   (r4-verified)
  {
    const int f = t;
    float wp[64];
    const float* wrow = Wp + (size_t)f * HH;
#pragma unroll
    for (int j = 0; j < 16; ++j) {
      float4 v = *(const float4*)(wrow + j * 4);
      wp[j * 4 + 0] = v.x; wp[j * 4 + 1] = v.y;
      wp[j * 4 + 2] = v.z; wp[j * 4 + 3] = v.w;
    }
    const float bpf = bp[f];
    for (int r = 0; r < 16; ++r) {
      float a = bpf;
#pragma unroll
      for (int k = 0; k < 64; k += 4) {
        float4 nv = *(const float4*)&s_nb[r][k];
        a += nv.x * wp[k] + nv.y * wp[k + 1] + nv.z * wp[k + 2] + nv.w * wp[k + 3];
      }
      float y = x[(size_t)(row0 + r) * FF + f] + a;
      s_y[r * 256 + f] = y;
    }
  }
  __syncthreads();

  // LayerNorm (r4-verified); wave w handles rows w*4 .. w*4+3
  for (int i = 0; i < 4; ++i) {
    const int r = w * 4 + i;
    float4 v = *(const float4*)&s_y[r * 256 + lane * 4];
    float sum = v.x + v.y + v.z + v.w;
    float ss  = v.x * v.x + v.y * v.y + v.z * v.z + v.w * v.w;
#pragma unroll
    for (int o = 32; o >= 1; o >>= 1) {
      sum += __shfl_xor(sum, o, 64);
      ss  += __shfl_xor(ss, o, 64);
    }
    const float mu  = sum * (1.0f / 256.0f);
    const float var = ss * (1.0f / 256.0f) - mu * mu;
    const float rs  = rsqrtf(var + 1e-5f);
    const int f0 = lane * 4;
    float4 g = *(const float4*)(gamma + f0);
    float4 b = *(const float4*)(beta + f0);
    float4 o4;
    o4.x = g.x * (v.x - mu) * rs + b.x;
    o4.y = g.y * (v.y - mu) * rs + b.y;
    o4.z = g.z * (v.z - mu) * rs + b.z;
    o4.w = g.w * (v.w - mu) * rs + b.w;
    *(float4*)(out + (size_t)(row0 + r) * FF + f0) = o4;
  }
}

extern "C" void kernel_launch(void* const* d_in, const int* in_sizes, int n_in,
                              void* d_out, int out_size, void* d_ws, size_t ws_size,
                              hipStream_t stream) {
  const float* x     = (const float*)d_in[0];
  const int*   adj   = (const int*)d_in[1];
  const float* Wt    = (const float*)d_in[2];
  const float* bt    = (const float*)d_in[3];
  // d_in[4] = Wa, d_in[5] = ba: provably dead (softmax scores are row-constant)
  const float* Wp    = (const float*)d_in[6];
  const float* bp    = (const float*)d_in[7];
  const float* gamma = (const float*)d_in[8];
  const float* beta  = (const float*)d_in[9];
  float* out = (float*)d_out;
  float*    h  = (float*)d_ws;                                   // 2 MB fp32
  uint16_t* hT = (uint16_t*)((char*)d_ws + (size_t)NN * HH * 4); // +1 MB bf16

  k1_h  <<<256, 256, 0, stream>>>(x, Wt, bt, h);
  k1b_hT<<<128, 256, 0, stream>>>(h, hT);
  k2_attn<<<512, 256, 0, stream>>>(x, adj, hT, Wp, bp, gamma, beta, out);
}

// Round 11
// 447.035 us; speedup vs baseline: 2.5821x; 1.0029x over previous
//
#include <hip/hip_runtime.h>
#include <stdint.h>

#define NN 8192
#define FF 256
#define HH 64

typedef __attribute__((ext_vector_type(8))) short bf16x8;
typedef __attribute__((ext_vector_type(4))) float f32x4;

__device__ __forceinline__ uint16_t f2bf(float f) {
  union { float f; uint32_t i; } c; c.f = f;
  uint32_t r = c.i + 0x7FFFu + ((c.i >> 16) & 1u);
  return (uint16_t)(r >> 16);
}

// ---------------------------------------------------------------------------
// K1 (VERIFIED r5/r7/r8, verbatim): h = x @ Wt^T + bt (fp32), h[node][c].
// ---------------------------------------------------------------------------
__global__ __launch_bounds__(256) void k1_h(
    const float* __restrict__ x, const float* __restrict__ Wt,
    const float* __restrict__ bt, float* __restrict__ h) {
  __shared__ float wtT[256 * 65];
  __shared__ float sbt[64];
  const int t = threadIdx.x;
  const int lane = t & 63;
  const int w = t >> 6;

  for (int i = 0; i < 64; ++i)
    wtT[t * 65 + i] = Wt[(size_t)i * FF + t];
  if (t < 64) sbt[t] = bt[t];
  __syncthreads();

  const int r0 = blockIdx.x * 32 + w * 8;
  const float binit = sbt[lane];
  float acc[8];
#pragma unroll
  for (int r = 0; r < 8; ++r) acc[r] = binit;

  for (int f4 = 0; f4 < FF; f4 += 4) {
    float4 xs[8];
#pragma unroll
    for (int r = 0; r < 8; ++r)
      xs[r] = *(const float4*)(x + (size_t)(r0 + r) * FF + f4);
    const float wt0 = wtT[(f4 + 0) * 65 + lane];
    const float wt1 = wtT[(f4 + 1) * 65 + lane];
    const float wt2 = wtT[(f4 + 2) * 65 + lane];
    const float wt3 = wtT[(f4 + 3) * 65 + lane];
#pragma unroll
    for (int r = 0; r < 8; ++r)
      acc[r] += xs[r].x * wt0 + xs[r].y * wt1 + xs[r].z * wt2 + xs[r].w * wt3;
  }
#pragma unroll
  for (int r = 0; r < 8; ++r)
    h[(size_t)(r0 + r) * HH + lane] = acc[r];
}

// ---------------------------------------------------------------------------
// K1b (VERIFIED r7/r8, verbatim): hT[c][n] = bf16(h[n][c]). grid=128.
// ---------------------------------------------------------------------------
__global__ __launch_bounds__(256) void k1b_hT(
    const float* __restrict__ h, uint16_t* __restrict__ hT) {
  __shared__ float s[64][65];
  const int t = threadIdx.x;
  const int n0 = blockIdx.x * 64;
  for (int i = 0; i < 16; ++i) {
    int idx = i * 256 + t;
    int r = idx >> 6, c = idx & 63;
    s[r][c] = h[(size_t)(n0 + r) * HH + c];
  }
  __syncthreads();
  for (int i = 0; i < 16; ++i) {
    int idx = i * 256 + t;
    int c = idx >> 6, n = idx & 63;
    hT[(size_t)c * NN + n0 + n] = f2bf(s[n][c]);
  }
}

// ---------------------------------------------------------------------------
// K2 = r8 VERIFIED structure (block 256, 4 waves, split-K 4, grid 512).
// SINGLE CHANGE vs r8: K-loop unrolled x2 with all 12 loads grouped ahead of
// the 8 MFMAs (2x memory-level parallelism). Chunk A = kb+8q, chunk B =
// kb+32+8q; af construction duplicated verbatim from the verified body.
// ---------------------------------------------------------------------------
__global__ __launch_bounds__(256) void k2_attn(
    const float* __restrict__ x, const int* __restrict__ adj,
    const uint16_t* __restrict__ hT, const float* __restrict__ Wp,
    const float* __restrict__ bp, const float* __restrict__ gamma,
    const float* __restrict__ beta, float* __restrict__ out) {
  __shared__ float s_part[4][16][64];   // 16 KB partial D
  __shared__ float s_nb[16][64];        // 4 KB neighbor post /deg
  __shared__ float s_y[16 * 256];       // 16 KB y = x + tf
  __shared__ int   s_deg[16];

  const int t    = threadIdx.x;
  const int w    = t >> 6;
  const int lane = t & 63;
  const int m    = lane & 15;
  const int q    = lane >> 4;
  const int row0 = blockIdx.x * 16;

  if (t < 16) s_deg[t] = 0;
  __syncthreads();

  const int kbeg = w * (NN / 4);
  const int kend = kbeg + (NN / 4);

  f32x4 acc0 = 0, acc1 = 0, acc2 = 0, acc3 = 0;
  int degm = 0;
  const int* __restrict__ arow = adj + (size_t)(row0 + m) * NN;
  const uint16_t* __restrict__ hrow = hT + (size_t)m * NN;

  for (int kb = kbeg; kb < kend; kb += 64) {
    const int k0 = kb + q * 8;        // chunk A octet
    const int k1 = k0 + 32;           // chunk B octet
    // ---- all loads first (12 in flight) ----
    int4 a0 = *(const int4*)(arow + k0);
    int4 a1 = *(const int4*)(arow + k0 + 4);
    int4 a2 = *(const int4*)(arow + k1);
    int4 a3 = *(const int4*)(arow + k1 + 4);
    bf16x8 b0 = *(const bf16x8*)(hrow + k0);
    bf16x8 b1 = *(const bf16x8*)(hrow + 16 * NN + k0);
    bf16x8 b2 = *(const bf16x8*)(hrow + 32 * NN + k0);
    bf16x8 b3 = *(const bf16x8*)(hrow + 48 * NN + k0);
    bf16x8 c0 = *(const bf16x8*)(hrow + k1);
    bf16x8 c1 = *(const bf16x8*)(hrow + 16 * NN + k1);
    bf16x8 c2 = *(const bf16x8*)(hrow + 32 * NN + k1);
    bf16x8 c3 = *(const bf16x8*)(hrow + 48 * NN + k1);
    // ---- af chunk A (verified construction) ----
    bf16x8 afA;
    afA[0] = a0.x ? (short)0x3F80 : (short)0;
    afA[1] = a0.y ? (short)0x3F80 : (short)0;
    afA[2] = a0.z ? (short)0x3F80 : (short)0;
    afA[3] = a0.w ? (short)0x3F80 : (short)0;
    afA[4] = a1.x ? (short)0x3F80 : (short)0;
    afA[5] = a1.y ? (short)0x3F80 : (short)0;
    afA[6] = a1.z ? (short)0x3F80 : (short)0;
    afA[7] = a1.w ? (short)0x3F80 : (short)0;
    // ---- af chunk B ----
    bf16x8 afB;
    afB[0] = a2.x ? (short)0x3F80 : (short)0;
    afB[1] = a2.y ? (short)0x3F80 : (short)0;
    afB[2] = a2.z ? (short)0x3F80 : (short)0;
    afB[3] = a2.w ? (short)0x3F80 : (short)0;
    afB[4] = a3.x ? (short)0x3F80 : (short)0;
    afB[5] = a3.y ? (short)0x3F80 : (short)0;
    afB[6] = a3.z ? (short)0x3F80 : (short)0;
    afB[7] = a3.w ? (short)0x3F80 : (short)0;
    // ---- 8 MFMAs ----
    acc0 = __builtin_amdgcn_mfma_f32_16x16x32_bf16(afA, b0, acc0, 0, 0, 0);
    acc1 = __builtin_amdgcn_mfma_f32_16x16x32_bf16(afA, b1, acc1, 0, 0, 0);
    acc2 = __builtin_amdgcn_mfma_f32_16x16x32_bf16(afA, b2, acc2, 0, 0, 0);
    acc3 = __builtin_amdgcn_mfma_f32_16x16x32_bf16(afA, b3, acc3, 0, 0, 0);
    acc0 = __builtin_amdgcn_mfma_f32_16x16x32_bf16(afB, c0, acc0, 0, 0, 0);
    acc1 = __builtin_amdgcn_mfma_f32_16x16x32_bf16(afB, c1, acc1, 0, 0, 0);
    acc2 = __builtin_amdgcn_mfma_f32_16x16x32_bf16(afB, c2, acc2, 0, 0, 0);
    acc3 = __builtin_amdgcn_mfma_f32_16x16x32_bf16(afB, c3, acc3, 0, 0, 0);
    // ---- deg (all 16 ints, each column once) ----
    degm += a0.x + a0.y + a0.z + a0.w + a1.x + a1.y + a1.z + a1.w;
    degm += a2.x + a2.y + a2.z + a2.w + a3.x + a3.y + a3.z + a3.w;
  }

  degm += __shfl_down(degm, 32, 64);
  degm += __shfl_down(degm, 16, 64);
  if (lane < 16) atomicAdd(&s_deg[lane], degm);

#pragma unroll
  for (int rg = 0; rg < 4; ++rg) {
    s_part[w][q * 4 + rg][ 0 + m] = acc0[rg];
    s_part[w][q * 4 + rg][16 + m] = acc1[rg];
    s_part[w][q * 4 + rg][32 + m] = acc2[rg];
    s_part[w][q * 4 + rg][48 + m] = acc3[rg];
  }
  __syncthreads();

  // cross-wave reduce + /deg  (r8 verbatim)
  for (int idx = t; idx < 16 * 64; idx += 256) {
    int r = idx >> 6, c = idx & 63;
    float s = s_part[0][r][c] + s_part[1][r][c] +
              s_part[2][r][c] + s_part[3][r][c];
    int d = s_deg[r];
    s_nb[r][c] = (d > 0) ? s / (float)d : 0.f;
  }
  __syncthreads();

  // tf = neighbor @ Wp^T + bp ; y = x + tf   (r4-verified, r8 verbatim)
  {
    const int f = t;
    float wp[64];
    const float* wrow = Wp + (size_t)f * HH;
#pragma unroll
    for (int j = 0; j < 16; ++j) {
      float4 v = *(const float4*)(wrow + j * 4);
      wp[j * 4 + 0] = v.x; wp[j * 4 + 1] = v.y;
      wp[j * 4 + 2] = v.z; wp[j * 4 + 3] = v.w;
    }
    const float bpf = bp[f];
    for (int r = 0; r < 16; ++r) {
      float a = bpf;
#pragma unroll
      for (int k = 0; k < 64; k += 4) {
        float4 nv = *(const float4*)&s_nb[r][k];
        a += nv.x * wp[k] + nv.y * wp[k + 1] + nv.z * wp[k + 2] + nv.w * wp[k + 3];
      }
      float y = x[(size_t)(row0 + r) * FF + f] + a;
      s_y[r * 256 + f] = y;
    }
  }
  __syncthreads();

  // LayerNorm (r4-verified, r8 verbatim); wave w handles rows w*4 .. w*4+3
  for (int i = 0; i < 4; ++i) {
    const int r = w * 4 + i;
    float4 v = *(const float4*)&s_y[r * 256 + lane * 4];
    float sum = v.x + v.y + v.z + v.w;
    float ss  = v.x * v.x + v.y * v.y + v.z * v.z + v.w * v.w;
#pragma unroll
    for (int o = 32; o >= 1; o >>= 1) {
      sum += __shfl_xor(sum, o, 64);
      ss  += __shfl_xor(ss, o, 64);
    }
    const float mu  = sum * (1.0f / 256.0f);
    const float var = ss * (1.0f / 256.0f) - mu * mu;
    const float rs  = rsqrtf(var + 1e-5f);
    const int f0 = lane * 4;
    float4 g = *(const float4*)(gamma + f0);
    float4 b = *(const float4*)(beta + f0);
    float4 o4;
    o4.x = g.x * (v.x - mu) * rs + b.x;
    o4.y = g.y * (v.y - mu) * rs + b.y;
    o4.z = g.z * (v.z - mu) * rs + b.z;
    o4.w = g.w * (v.w - mu) * rs + b.w;
    *(float4*)(out + (size_t)(row0 + r) * FF + f0) = o4;
  }
}

extern "C" void kernel_launch(void* const* d_in, const int* in_sizes, int n_in,
                              void* d_out, int out_size, void* d_ws, size_t ws_size,
                              hipStream_t stream) {
  const float* x     = (const float*)d_in[0];
  const int*   adj   = (const int*)d_in[1];
  const float* Wt    = (const float*)d_in[2];
  const float* bt    = (const float*)d_in[3];
  // d_in[4] = Wa, d_in[5] = ba: provably dead (softmax scores are row-constant)
  const float* Wp    = (const float*)d_in[6];
  const float* bp    = (const float*)d_in[7];
  const float* gamma = (const float*)d_in[8];
  const float* beta  = (const float*)d_in[9];
  float* out = (float*)d_out;
  float*    h  = (float*)d_ws;                                   // 2 MB fp32
  uint16_t* hT = (uint16_t*)((char*)d_ws + (size_t)NN * HH * 4); // +1 MB bf16

  k1_h  <<<256, 256, 0, stream>>>(x, Wt, bt, h);
  k1b_hT<<<128, 256, 0, stream>>>(h, hT);
  k2_attn<<<512, 256, 0, stream>>>(x, adj, hT, Wp, bp, gamma, beta, out);
}

// Round 13
// 440.681 us; speedup vs baseline: 2.6193x; 1.0144x over previous
//
#include <hip/hip_runtime.h>
#include <stdint.h>

#define NN 8192
#define FF 256
#define HH 64

typedef __attribute__((ext_vector_type(8))) short bf16x8;
typedef __attribute__((ext_vector_type(4))) float f32x4;

__device__ __forceinline__ uint16_t f2bf(float f) {
  union { float f; uint32_t i; } c; c.f = f;
  uint32_t r = c.i + 0x7FFFu + ((c.i >> 16) & 1u);
  return (uint16_t)(r >> 16);
}

// ---------------------------------------------------------------------------
// K1 (VERIFIED r5..r11 core) + tail that zeroes this block's slice of the
// global split-K accumulators (nb_sum rows 32b..32b+31, deg_g same rows).
// Stream order guarantees zeroing completes before k2 launches.
// ---------------------------------------------------------------------------
__global__ __launch_bounds__(256) void k1_h(
    const float* __restrict__ x, const float* __restrict__ Wt,
    const float* __restrict__ bt, float* __restrict__ h,
    float* __restrict__ nb_sum, int* __restrict__ deg_g) {
  __shared__ float wtT[256 * 65];
  __shared__ float sbt[64];
  const int t = threadIdx.x;
  const int lane = t & 63;
  const int w = t >> 6;

  for (int i = 0; i < 64; ++i)
    wtT[t * 65 + i] = Wt[(size_t)i * FF + t];
  if (t < 64) sbt[t] = bt[t];
  __syncthreads();

  const int r0 = blockIdx.x * 32 + w * 8;
  const float binit = sbt[lane];
  float acc[8];
#pragma unroll
  for (int r = 0; r < 8; ++r) acc[r] = binit;

  for (int f4 = 0; f4 < FF; f4 += 4) {
    float4 xs[8];
#pragma unroll
    for (int r = 0; r < 8; ++r)
      xs[r] = *(const float4*)(x + (size_t)(r0 + r) * FF + f4);
    const float wt0 = wtT[(f4 + 0) * 65 + lane];
    const float wt1 = wtT[(f4 + 1) * 65 + lane];
    const float wt2 = wtT[(f4 + 2) * 65 + lane];
    const float wt3 = wtT[(f4 + 3) * 65 + lane];
#pragma unroll
    for (int r = 0; r < 8; ++r)
      acc[r] += xs[r].x * wt0 + xs[r].y * wt1 + xs[r].z * wt2 + xs[r].w * wt3;
  }
#pragma unroll
  for (int r = 0; r < 8; ++r)
    h[(size_t)(r0 + r) * HH + lane] = acc[r];

  // ---- zero accumulators for rows 32b..32b+31 (2048 floats = 512 float4) ----
  float4 z = {0.f, 0.f, 0.f, 0.f};
  float4* nbz = (float4*)(nb_sum + (size_t)blockIdx.x * 32 * HH);
  for (int i = t; i < 512; i += 256) nbz[i] = z;
  if (t < 32) deg_g[blockIdx.x * 32 + t] = 0;
}

// ---------------------------------------------------------------------------
// K1b (VERIFIED r7..r11, verbatim): hT[c][n] = bf16(h[n][c]). grid=128.
// ---------------------------------------------------------------------------
__global__ __launch_bounds__(256) void k1b_hT(
    const float* __restrict__ h, uint16_t* __restrict__ hT) {
  __shared__ float s[64][65];
  const int t = threadIdx.x;
  const int n0 = blockIdx.x * 64;
  for (int i = 0; i < 16; ++i) {
    int idx = i * 256 + t;
    int r = idx >> 6, c = idx & 63;
    s[r][c] = h[(size_t)(n0 + r) * HH + c];
  }
  __syncthreads();
  for (int i = 0; i < 16; ++i) {
    int idx = i * 256 + t;
    int c = idx >> 6, n = idx & 63;
    hT[(size_t)c * NN + n0 + n] = f2bf(s[n][c]);
  }
}

// ---------------------------------------------------------------------------
// K2: r8/r11 VERIFIED core through the LDS reduce, byte-identical geometry
// (BM=16, 4 waves, block 256). Grid-level split-K 2: block = (group g,
// half): rows g*16..g*16+15, K range half*4096 + w*1024 .. +1024.
// After the reduce, atomically accumulate partial sums into global nb_sum /
// deg_g (device-scope). No epilogue here. grid = 1024.
// ---------------------------------------------------------------------------
__global__ __launch_bounds__(256) void k2_attn(
    const int* __restrict__ adj, const uint16_t* __restrict__ hT,
    float* __restrict__ nb_sum, int* __restrict__ deg_g) {
  __shared__ float s_part[4][16][64];   // 16 KB partial D
  __shared__ int   s_deg[16];

  const int t    = threadIdx.x;
  const int w    = t >> 6;
  const int lane = t & 63;
  const int m    = lane & 15;
  const int q    = lane >> 4;
  const int g    = blockIdx.x >> 1;
  const int half = blockIdx.x & 1;
  const int row0 = g * 16;

  if (t < 16) s_deg[t] = 0;
  __syncthreads();

  const int kbeg = half * (NN / 2) + w * (NN / 8);
  const int kend = kbeg + (NN / 8);

  f32x4 acc0 = 0, acc1 = 0, acc2 = 0, acc3 = 0;
  int degm = 0;
  const int* __restrict__ arow = adj + (size_t)(row0 + m) * NN;
  const uint16_t* __restrict__ hrow = hT + (size_t)m * NN;

  for (int kb = kbeg; kb < kend; kb += 64) {
    const int k0 = kb + q * 8;        // chunk A octet
    const int k1 = k0 + 32;           // chunk B octet
    // ---- all loads first (r11-verified x2 unroll) ----
    int4 a0 = *(const int4*)(arow + k0);
    int4 a1 = *(const int4*)(arow + k0 + 4);
    int4 a2 = *(const int4*)(arow + k1);
    int4 a3 = *(const int4*)(arow + k1 + 4);
    bf16x8 b0 = *(const bf16x8*)(hrow + k0);
    bf16x8 b1 = *(const bf16x8*)(hrow + 16 * NN + k0);
    bf16x8 b2 = *(const bf16x8*)(hrow + 32 * NN + k0);
    bf16x8 b3 = *(const bf16x8*)(hrow + 48 * NN + k0);
    bf16x8 c0 = *(const bf16x8*)(hrow + k1);
    bf16x8 c1 = *(const bf16x8*)(hrow + 16 * NN + k1);
    bf16x8 c2 = *(const bf16x8*)(hrow + 32 * NN + k1);
    bf16x8 c3 = *(const bf16x8*)(hrow + 48 * NN + k1);
    // ---- af chunk A (r7-verified construction) ----
    bf16x8 afA;
    afA[0] = a0.x ? (short)0x3F80 : (short)0;
    afA[1] = a0.y ? (short)0x3F80 : (short)0;
    afA[2] = a0.z ? (short)0x3F80 : (short)0;
    afA[3] = a0.w ? (short)0x3F80 : (short)0;
    afA[4] = a1.x ? (short)0x3F80 : (short)0;
    afA[5] = a1.y ? (short)0x3F80 : (short)0;
    afA[6] = a1.z ? (short)0x3F80 : (short)0;
    afA[7] = a1.w ? (short)0x3F80 : (short)0;
    // ---- af chunk B ----
    bf16x8 afB;
    afB[0] = a2.x ? (short)0x3F80 : (short)0;
    afB[1] = a2.y ? (short)0x3F80 : (short)0;
    afB[2] = a2.z ? (short)0x3F80 : (short)0;
    afB[3] = a2.w ? (short)0x3F80 : (short)0;
    afB[4] = a3.x ? (short)0x3F80 : (short)0;
    afB[5] = a3.y ? (short)0x3F80 : (short)0;
    afB[6] = a3.z ? (short)0x3F80 : (short)0;
    afB[7] = a3.w ? (short)0x3F80 : (short)0;
    // ---- 8 MFMAs ----
    acc0 = __builtin_amdgcn_mfma_f32_16x16x32_bf16(afA, b0, acc0, 0, 0, 0);
    acc1 = __builtin_amdgcn_mfma_f32_16x16x32_bf16(afA, b1, acc1, 0, 0, 0);
    acc2 = __builtin_amdgcn_mfma_f32_16x16x32_bf16(afA, b2, acc2, 0, 0, 0);
    acc3 = __builtin_amdgcn_mfma_f32_16x16x32_bf16(afA, b3, acc3, 0, 0, 0);
    acc0 = __builtin_amdgcn_mfma_f32_16x16x32_bf16(afB, c0, acc0, 0, 0, 0);
    acc1 = __builtin_amdgcn_mfma_f32_16x16x32_bf16(afB, c1, acc1, 0, 0, 0);
    acc2 = __builtin_amdgcn_mfma_f32_16x16x32_bf16(afB, c2, acc2, 0, 0, 0);
    acc3 = __builtin_amdgcn_mfma_f32_16x16x32_bf16(afB, c3, acc3, 0, 0, 0);
    // ---- deg ----
    degm += a0.x + a0.y + a0.z + a0.w + a1.x + a1.y + a1.z + a1.w;
    degm += a2.x + a2.y + a2.z + a2.w + a3.x + a3.y + a3.z + a3.w;
  }

  degm += __shfl_down(degm, 32, 64);
  degm += __shfl_down(degm, 16, 64);
  if (lane < 16) atomicAdd(&s_deg[lane], degm);

#pragma unroll
  for (int rg = 0; rg < 4; ++rg) {
    s_part[w][q * 4 + rg][ 0 + m] = acc0[rg];
    s_part[w][q * 4 + rg][16 + m] = acc1[rg];
    s_part[w][q * 4 + rg][32 + m] = acc2[rg];
    s_part[w][q * 4 + rg][48 + m] = acc3[rg];
  }
  __syncthreads();

  // cross-wave reduce (r8 verbatim map) -> global atomic accumulate
  for (int idx = t; idx < 16 * 64; idx += 256) {
    int r = idx >> 6, c = idx & 63;
    float s = s_part[0][r][c] + s_part[1][r][c] +
              s_part[2][r][c] + s_part[3][r][c];
    atomicAdd(&nb_sum[(size_t)(row0 + r) * HH + c], s);
  }
  if (t < 16) atomicAdd(&deg_g[row0 + t], s_deg[t]);
}

// ---------------------------------------------------------------------------
// K3: epilogue, VERBATIM r4/r8-verified maps. Reads nb_sum/deg_g, forms
// s_nb, then tf = nb @ Wp^T + bp, y = x + tf, LayerNorm -> out.
// block = 256, 16 rows/block, grid = 512.
// ---------------------------------------------------------------------------
__global__ __launch_bounds__(256) void k3_epi(
    const float* __restrict__ x, const float* __restrict__ nb_sum,
    const int* __restrict__ deg_g, const float* __restrict__ Wp,
    const float* __restrict__ bp, const float* __restrict__ gamma,
    const float* __restrict__ beta, float* __restrict__ out) {
  __shared__ float s_nb[16][64];
  __shared__ float s_y[16 * 256];

  const int t    = threadIdx.x;
  const int w    = t >> 6;
  const int lane = t & 63;
  const int row0 = blockIdx.x * 16;

  for (int idx = t; idx < 16 * 64; idx += 256) {
    int r = idx >> 6, c = idx & 63;
    int d = deg_g[row0 + r];
    float s = nb_sum[(size_t)(row0 + r) * HH + c];
    s_nb[r][c] = (d > 0) ? s / (float)d : 0.f;
  }
  __syncthreads();

  // tf = neighbor @ Wp^T + bp ; y = x + tf   (r4-verified, r8 verbatim)
  {
    const int f = t;
    float wp[64];
    const float* wrow = Wp + (size_t)f * HH;
#pragma unroll
    for (int j = 0; j < 16; ++j) {
      float4 v = *(const float4*)(wrow + j * 4);
      wp[j * 4 + 0] = v.x; wp[j * 4 + 1] = v.y;
      wp[j * 4 + 2] = v.z; wp[j * 4 + 3] = v.w;
    }
    const float bpf = bp[f];
    for (int r = 0; r < 16; ++r) {
      float a = bpf;
#pragma unroll
      for (int k = 0; k < 64; k += 4) {
        float4 nv = *(const float4*)&s_nb[r][k];
        a += nv.x * wp[k] + nv.y * wp[k + 1] + nv.z * wp[k + 2] + nv.w * wp[k + 3];
      }
      float y = x[(size_t)(row0 + r) * FF + f] + a;
      s_y[r * 256 + f] = y;
    }
  }
  __syncthreads();

  // LayerNorm (r4-verified, r8 verbatim); wave w handles rows w*4 .. w*4+3
  for (int i = 0; i < 4; ++i) {
    const int r = w * 4 + i;
    float4 v = *(const float4*)&s_y[r * 256 + lane * 4];
    float sum = v.x + v.y + v.z + v.w;
    float ss  = v.x * v.x + v.y * v.y + v.z * v.z + v.w * v.w;
#pragma unroll
    for (int o = 32; o >= 1; o >>= 1) {
      sum += __shfl_xor(sum, o, 64);
      ss  += __shfl_xor(ss, o, 64);
    }
    const float mu  = sum * (1.0f / 256.0f);
    const float var = ss * (1.0f / 256.0f) - mu * mu;
    const float rs  = rsqrtf(var + 1e-5f);
    const int f0 = lane * 4;
    float4 g = *(const float4*)(gamma + f0);
    float4 b = *(const float4*)(beta + f0);
    float4 o4;
    o4.x = g.x * (v.x - mu) * rs + b.x;
    o4.y = g.y * (v.y - mu) * rs + b.y;
    o4.z = g.z * (v.z - mu) * rs + b.z;
    o4.w = g.w * (v.w - mu) * rs + b.w;
    *(float4*)(out + (size_t)(row0 + r) * FF + f0) = o4;
  }
}

extern "C" void kernel_launch(void* const* d_in, const int* in_sizes, int n_in,
                              void* d_out, int out_size, void* d_ws, size_t ws_size,
                              hipStream_t stream) {
  const float* x     = (const float*)d_in[0];
  const int*   adj   = (const int*)d_in[1];
  const float* Wt    = (const float*)d_in[2];
  const float* bt    = (const float*)d_in[3];
  // d_in[4] = Wa, d_in[5] = ba: provably dead (softmax scores are row-constant)
  const float* Wp    = (const float*)d_in[6];
  const float* bp    = (const float*)d_in[7];
  const float* gamma = (const float*)d_in[8];
  const float* beta  = (const float*)d_in[9];
  float* out = (float*)d_out;

  // ws layout: hT 1 MB | nb_sum 2 MB | deg_g 32 KB | h 2 MB
  uint16_t* hT     = (uint16_t*)d_ws;
  float*    nb_sum = (float*)((char*)d_ws + (1u << 20));
  int*      deg_g  = (int*)((char*)d_ws + (3u << 20));
  float*    h      = (float*)((char*)d_ws + (3u << 20) + (1u << 18));

  k1_h  <<<256, 256, 0, stream>>>(x, Wt, bt, h, nb_sum, deg_g);
  k1b_hT<<<128, 256, 0, stream>>>(h, hT);
  k2_attn<<<1024, 256, 0, stream>>>(adj, hT, nb_sum, deg_g);
  k3_epi<<<512, 256, 0, stream>>>(x, nb_sum, deg_g, Wp, bp, gamma, beta, out);
}